// Round 5
// baseline (89.996 us; speedup 1.0000x reference)
//
#include <hip/hip_runtime.h>
#include <hip/hip_fp16.h>
#include <math.h>

// StripePolynomial2d, round 5.
// - One output row per block (w uniform) -> stripe-0 candidates (<=2 segs)
//   fetched from ws via VMEM and selected with cndmask: -1/3 LDS traffic.
// - 2 pixels/thread (consecutive h): half the waves, dwordx2 global IO.
// - Stripes 1/2 unchanged: fp16 records in LDS, ds_read_b128 + ds_read_b32.
// Record layout (32 B per (ec,seg)):
//   [c0_0,c0_1][c1_0,c1_1][c2_0,c2_1][c0_2,c1_2][c2_2,0] + 12 B pad.

#define NREC 576              // 9 ec * 64 seg
#define CBYTES (NREC * 32)

__device__ __forceinline__ __half2 u2h2(unsigned int u) {
    __half2 h; __builtin_memcpy(&h, &u, 4); return h;
}
__device__ __forceinline__ unsigned int h22u(__half2 h) {
    unsigned int u; __builtin_memcpy(&u, &h, 4); return u;
}

__device__ __forceinline__ void coeff_compute(const float* __restrict__ Wt, int r,
                                              unsigned int rec[8]) {
    int ec  = r >> 6;
    int seg = r & 63;
    int e   = ec / 3;
    int c   = ec - e * 3;
    int nb  = 2 * seg;
    float c0[3], c1[3], c2[3];
    #pragma unroll
    for (int o = 0; o < 3; ++o) {
        float w0, w1, w2;
        if (e == 0) {
            const float* p0 = Wt + ((0 * 3 + o) * 3 + c) * 129 + nb;
            const float* p1 = Wt + ((1 * 3 + o) * 3 + c) * 129 + nb;
            w0 = p0[0] + p1[0]; w1 = p0[1] + p1[1]; w2 = p0[2] + p1[2];
        } else {
            const float* p = Wt + (((e + 1) * 3 + o) * 3 + c) * 129 + nb;
            w0 = p[0]; w1 = p[1]; w2 = p[2];
        }
        c0[o] = 0.25f  * w1;
        c1[o] = 0.125f * (w2 - w0);
        c2[o] = 0.125f * (w0 + w2) - 0.25f * w1;
    }
    rec[0] = h22u(__floats2half2_rn(c0[0], c0[1]));
    rec[1] = h22u(__floats2half2_rn(c1[0], c1[1]));
    rec[2] = h22u(__floats2half2_rn(c2[0], c2[1]));
    rec[3] = h22u(__floats2half2_rn(c0[2], c1[2]));
    rec[4] = h22u(__floats2half2_rn(c2[2], 0.0f));
    rec[5] = 0u; rec[6] = 0u; rec[7] = 0u;
}

__global__ __launch_bounds__(256) void coeff_kernel(const float* __restrict__ Wt,
                                                    uint4* __restrict__ ws) {
    int r = blockIdx.x * 256 + threadIdx.x;
    if (r >= NREC) return;
    unsigned int rec[8];
    coeff_compute(Wt, r, rec);
    ws[2 * r]     = make_uint4(rec[0], rec[1], rec[2], rec[3]);
    ws[2 * r + 1] = make_uint4(rec[4], rec[5], rec[6], rec[7]);
}

__device__ __forceinline__ void horner_acc(uint4 A, unsigned int Bv, float xl,
                                           float& a0, float& a1, float& a2) {
    float2 k0 = __half22float2(u2h2(A.x));  // c0_0, c0_1
    float2 k1 = __half22float2(u2h2(A.y));  // c1_0, c1_1
    float2 k2 = __half22float2(u2h2(A.z));  // c2_0, c2_1
    float2 k3 = __half22float2(u2h2(A.w));  // c0_2, c1_2
    float  c22 = __half2float(__low2half(u2h2(Bv)));
    a0 += fmaf(fmaf(k2.x, xl, k1.x), xl, k0.x);
    a1 += fmaf(fmaf(k2.y, xl, k1.y), xl, k0.y);
    a2 += fmaf(fmaf(c22,  xl, k3.y), xl, k3.x);
}

template <bool FROM_WS>
__global__ __launch_bounds__(256) void stripe_main(
    const float* __restrict__ x, const float* __restrict__ Wt,
    const uint4* __restrict__ ws, float* __restrict__ out)
{
    __shared__ uint4 lw4[NREC * 2];   // 18432 B
    const unsigned int* lw = (const unsigned int*)lw4;
    const int tid = threadIdx.x;

    if (FROM_WS) {
        #pragma unroll
        for (int i = 0; i < 5; ++i) {
            int idx = i * 256 + tid;
            if (idx < NREC * 2) lw4[idx] = ws[idx];
        }
    } else {
        for (int r = tid; r < NREC; r += 256) {
            unsigned int rec[8];
            coeff_compute(Wt, r, rec);
            lw4[2 * r]     = make_uint4(rec[0], rec[1], rec[2], rec[3]);
            lw4[2 * r + 1] = make_uint4(rec[4], rec[5], rec[6], rec[7]);
        }
    }

    const int w = blockIdx.x;      // one row per block: w uniform
    const int b = blockIdx.y;
    const int h = tid * 2;

    constexpr double RATIO = 512.0 / 513.0;
    constexpr double CX = 0x1.6a09e667f3bcdp-1;  // cos(f64 pi/4)
    constexpr double SY = 0x1.6a09e667f3bccp-1;  // sin(f64 pi/4), 1 ulp lower
    constexpr double S0 = RATIO * 64.0 / 511.0;
    constexpr double R2MAX = CX * 511.0 + SY * 511.0;
    constexpr double S2 = RATIO * 64.0 / R2MAX;
    constexpr double MN3 = -(SY * 511.0);
    constexpr double MX3 = CX * 511.0;
    constexpr double S3 = RATIO * 64.0 / (MX3 - MN3);

    const float wf = (float)w, hf = (float)h, hf1 = (float)(h + 1);
    const float q0  = wf * (float)S0;                       // uniform, >= 0
    const float wcx2 = wf * (float)(CX * S2);
    const float q1a = fmaf(hf,  (float)(SY * S2), wcx2);
    const float q1b = fmaf(hf1, (float)(SY * S2), wcx2);
    const float wcx3 = fmaf(wf, (float)(CX * S3), (float)(-MN3 * S3));
    const float q2a = fmaf(hf,  (float)(-(SY * S3)), wcx3);
    const float q2b = fmaf(hf1, (float)(-(SY * S3)), wcx3);

    // ---- stripe-0 candidate records (uniform: only 2 possible segments) ----
    const float s0f = floorf(q0);
    const int   s0  = (int)s0f;
    const int   s1  = min(s0 + 1, 63);
    const float s1f = (float)s1;
    const float thr = s0f + 1.0f;
    uint4 cA[3], cB[3]; unsigned int cA1[3], cB1[3];
    if (FROM_WS) {
        #pragma unroll
        for (int c = 0; c < 3; ++c) {
            int rA = (c << 6) + s0, rB = (c << 6) + s1;
            cA[c]  = ws[2 * rA];
            cA1[c] = ((const unsigned int*)ws)[8 * rA + 4];
            cB[c]  = ws[2 * rB];
            cB1[c] = ((const unsigned int*)ws)[8 * rB + 4];
        }
    }
    __syncthreads();
    if (!FROM_WS) {
        #pragma unroll
        for (int c = 0; c < 3; ++c) {
            int rA = (c << 6) + s0, rB = (c << 6) + s1;
            cA[c]  = lw4[2 * rA];
            cA1[c] = lw[8 * rA + 4];
            cB[c]  = lw4[2 * rB];
            cB1[c] = lw[8 * rB + 4];
        }
    }

    const int base = ((b * 3) << 18) + (w << 9) + h;
    float2 xv[3];
    #pragma unroll
    for (int c = 0; c < 3; ++c)
        xv[c] = *(const float2*)(x + base + (c << 18));

    float2 oacc[3];

    #pragma unroll
    for (int px = 0; px < 2; ++px) {
        const float q1 = px ? q1b : q1a;
        const float q2 = px ? q2b : q2a;

        // ---- phase A + LDS issue for stripes 1/2 (6 steps) ----
        uint4        A[6];
        unsigned int Bv[6];
        float        xls[6];
        #pragma unroll
        for (int s = 0; s < 6; ++s) {
            int   c  = s - 3 * (s / 3);
            float xc = px ? xv[c].y : xv[c].x;
            float q  = (s < 3) ? q1 : q2;
            float tn   = fmaf(xc, 0.125f, q);
            float segf = fminf(fmaxf(floorf(tn), 0.0f), 63.0f);
            int   seg  = (int)segf;
            xls[s] = fmaf(tn - segf, 2.0f, -1.0f);
            const unsigned int* rp = lw + (((s + 3) << 6) << 3) + (seg << 3);
            A[s]  = *(const uint4*)rp;   // ds_read_b128
            Bv[s] = rp[4];               // ds_read_b32
        }

        // ---- stripe 0 (VALU only, overlaps LDS latency) ----
        float a0 = 0.f, a1 = 0.f, a2 = 0.f;
        #pragma unroll
        for (int c = 0; c < 3; ++c) {
            float xc = px ? xv[c].y : xv[c].x;
            float tn = fmaf(xc, 0.125f, q0);
            bool  up = tn >= thr;
            float segf = up ? s1f : s0f;
            float xl   = fmaf(tn - segf, 2.0f, -1.0f);
            uint4 K4;
            K4.x = up ? cB[c].x : cA[c].x;
            K4.y = up ? cB[c].y : cA[c].y;
            K4.z = up ? cB[c].z : cA[c].z;
            K4.w = up ? cB[c].w : cA[c].w;
            unsigned int K1 = up ? cB1[c] : cA1[c];
            horner_acc(K4, K1, xl, a0, a1, a2);
        }

        // ---- stripes 1/2 Horner ----
        #pragma unroll
        for (int s = 0; s < 6; ++s)
            horner_acc(A[s], Bv[s], xls[s], a0, a1, a2);

        if (px == 0) { oacc[0].x = a0; oacc[1].x = a1; oacc[2].x = a2; }
        else         { oacc[0].y = a0; oacc[1].y = a1; oacc[2].y = a2; }
    }

    #pragma unroll
    for (int o = 0; o < 3; ++o)
        *(float2*)(out + base + (o << 18)) = oacc[o];
}

extern "C" void kernel_launch(void* const* d_in, const int* in_sizes, int n_in,
                              void* d_out, int out_size, void* d_ws, size_t ws_size,
                              hipStream_t stream) {
    const float* x  = (const float*)d_in[0]; // [8,3,512,512]
    const float* Wt = (const float*)d_in[1]; // [4,3,3,129]
    float* out = (float*)d_out;              // [8,3,512,512]

    dim3 block(256);
    dim3 grid(512, 8);   // one row (512 px) per block, 2 px/thread

    if (ws_size >= (size_t)CBYTES) {
        uint4* ws = (uint4*)d_ws;
        hipLaunchKernelGGL(coeff_kernel, dim3(3), block, 0, stream, Wt, ws);
        hipLaunchKernelGGL((stripe_main<true>), grid, block, 0, stream, x, Wt, ws, out);
    } else {
        hipLaunchKernelGGL((stripe_main<false>), grid, block, 0, stream,
                           x, Wt, (const uint4*)nullptr, out);
    }
}

// Round 6
// 83.006 us; speedup vs baseline: 1.0842x; 1.0842x over previous
//
#include <hip/hip_runtime.h>
#include <hip/hip_fp16.h>
#include <math.h>

// StripePolynomial2d, round 6: single dispatch + persistent grid-stride blocks.
// - Coeff table (fp16 monomial form, 576 records x 32 B) built in-kernel into
//   LDS once per block; no coeff_kernel, no ws dependency.
// - 2048 blocks (8/CU by LDS), each handles 4 tiles of 256 pixels -> staging
//   and barrier amortized 4x vs R4.
// - Inner loop identical to R4 (phase A seg/xl, phase B batched ds_read_b128 +
//   ds_read_b32, phase C cvt+Horner). absmax bit-identical to R4.

#define NREC 576              // 9 ec * 64 seg
#define NTILE 8192            // 8 imgs * 1024 tiles
#define NBLK 2048

__device__ __forceinline__ __half2 u2h2(unsigned int u) {
    __half2 h; __builtin_memcpy(&h, &u, 4); return h;
}
__device__ __forceinline__ unsigned int h22u(__half2 h) {
    unsigned int u; __builtin_memcpy(&u, &h, 4); return u;
}

__device__ __forceinline__ void coeff_compute(const float* __restrict__ Wt, int r,
                                              unsigned int rec[8]) {
    int ec  = r >> 6;
    int seg = r & 63;
    int e   = ec / 3;
    int c   = ec - e * 3;
    int nb  = 2 * seg;
    float c0[3], c1[3], c2[3];
    #pragma unroll
    for (int o = 0; o < 3; ++o) {
        float w0, w1, w2;
        if (e == 0) {
            const float* p0 = Wt + ((0 * 3 + o) * 3 + c) * 129 + nb;
            const float* p1 = Wt + ((1 * 3 + o) * 3 + c) * 129 + nb;
            w0 = p0[0] + p1[0]; w1 = p0[1] + p1[1]; w2 = p0[2] + p1[2];
        } else {
            const float* p = Wt + (((e + 1) * 3 + o) * 3 + c) * 129 + nb;
            w0 = p[0]; w1 = p[1]; w2 = p[2];
        }
        c0[o] = 0.25f  * w1;
        c1[o] = 0.125f * (w2 - w0);
        c2[o] = 0.125f * (w0 + w2) - 0.25f * w1;
    }
    rec[0] = h22u(__floats2half2_rn(c0[0], c0[1]));
    rec[1] = h22u(__floats2half2_rn(c1[0], c1[1]));
    rec[2] = h22u(__floats2half2_rn(c2[0], c2[1]));
    rec[3] = h22u(__floats2half2_rn(c0[2], c1[2]));
    rec[4] = h22u(__floats2half2_rn(c2[2], 0.0f));
    rec[5] = 0u; rec[6] = 0u; rec[7] = 0u;
}

__global__ __launch_bounds__(256) void stripe_all(
    const float* __restrict__ x, const float* __restrict__ Wt,
    float* __restrict__ out)
{
    __shared__ uint4 lw4[NREC * 2];   // 18432 B
    const unsigned int* lw = (const unsigned int*)lw4;
    const int tid = threadIdx.x;

    // ---- build coeff table once per block ----
    for (int r = tid; r < NREC; r += 256) {
        unsigned int rec[8];
        coeff_compute(Wt, r, rec);
        lw4[2 * r]     = make_uint4(rec[0], rec[1], rec[2], rec[3]);
        lw4[2 * r + 1] = make_uint4(rec[4], rec[5], rec[6], rec[7]);
    }
    __syncthreads();

    // q_e = pos_e/8 + 32, f32 from compile-time f64 constants.
    constexpr double RATIO = 512.0 / 513.0;
    constexpr double CX = 0x1.6a09e667f3bcdp-1;  // cos(f64 pi/4)
    constexpr double SY = 0x1.6a09e667f3bccp-1;  // sin(f64 pi/4), 1 ulp lower
    constexpr double S0 = RATIO * 64.0 / 511.0;
    constexpr double R2MAX = CX * 511.0 + SY * 511.0;
    constexpr double S2 = RATIO * 64.0 / R2MAX;
    constexpr double MN3 = -(SY * 511.0);
    constexpr double MX3 = CX * 511.0;
    constexpr double S3 = RATIO * 64.0 / (MX3 - MN3);

    for (int t = blockIdx.x; t < NTILE; t += NBLK) {
        const int b = t >> 10;
        const int p = ((t & 1023) << 8) + tid;
        const int w = p >> 9;
        const int h = p & 511;

        const float wf = (float)w, hf = (float)h;
        float qe[3];
        qe[0] = wf * (float)S0;
        qe[1] = fmaf(hf, (float)(SY * S2), wf * (float)(CX * S2));
        qe[2] = fmaf(hf, (float)(-(SY * S3)),
                     fmaf(wf, (float)(CX * S3), (float)(-MN3 * S3)));

        const int xbase = ((b * 3) << 18) + p;
        float xv[3];
        xv[0] = x[xbase];
        xv[1] = x[xbase + (1 << 18)];
        xv[2] = x[xbase + (2 << 18)];

        // ---- Phase A: all 9 (seg, xl) ----
        int   segi[9];
        float xls[9];
        #pragma unroll
        for (int s = 0; s < 9; ++s) {
            int e = s / 3, c = s - 3 * (s / 3);
            float tn   = fmaf(xv[c], 0.125f, qe[e]);
            float segf = fminf(fmaxf(floorf(tn), 0.0f), 63.0f);
            segi[s] = (int)segf;
            xls[s]  = fmaf(tn - segf, 2.0f, -1.0f);
        }

        // ---- Phase B: batch all LDS reads ----
        uint4        A[9];
        unsigned int Bv[9];
        #pragma unroll
        for (int s = 0; s < 9; ++s) {
            const unsigned int* rp = lw + ((s * 64 + segi[s]) << 3);
            A[s]  = *(const uint4*)rp;   // ds_read_b128
            Bv[s] = rp[4];               // ds_read_b32
        }

        // ---- Phase C: convert + Horner + accumulate ----
        float acc0 = 0.f, acc1 = 0.f, acc2 = 0.f;
        #pragma unroll
        for (int s = 0; s < 9; ++s) {
            float  xl  = xls[s];
            float2 k0 = __half22float2(u2h2(A[s].x));  // c0_0, c0_1
            float2 k1 = __half22float2(u2h2(A[s].y));  // c1_0, c1_1
            float2 k2 = __half22float2(u2h2(A[s].z));  // c2_0, c2_1
            float2 k3 = __half22float2(u2h2(A[s].w));  // c0_2, c1_2
            float  c22 = __half2float(__low2half(u2h2(Bv[s])));
            acc0 += fmaf(fmaf(k2.x, xl, k1.x), xl, k0.x);
            acc1 += fmaf(fmaf(k2.y, xl, k1.y), xl, k0.y);
            acc2 += fmaf(fmaf(c22,  xl, k3.y), xl, k3.x);
        }

        float* op = out + ((b * 3) << 18) + p;
        op[0]       = acc0;
        op[1 << 18] = acc1;
        op[2 << 18] = acc2;
    }
}

extern "C" void kernel_launch(void* const* d_in, const int* in_sizes, int n_in,
                              void* d_out, int out_size, void* d_ws, size_t ws_size,
                              hipStream_t stream) {
    const float* x  = (const float*)d_in[0]; // [8,3,512,512]
    const float* Wt = (const float*)d_in[1]; // [4,3,3,129]
    float* out = (float*)d_out;              // [8,3,512,512]

    hipLaunchKernelGGL(stripe_all, dim3(NBLK), dim3(256), 0, stream, x, Wt, out);
}